// Round 7
// baseline (1569.600 us; speedup 1.0000x reference)
//
#include <hip/hip_runtime.h>
#include <hip/hip_bf16.h>

// GRU-D fused scan, LDS + readlane-broadcast edition (resubmit: R6 bench was
// an infra failure — container died twice; no kernel evidence obtained).
// R5 diagnosis: ~600 cyc/step of unhideable latency in the h round trip
// (global store -> vmcnt drain -> s_dcache_inv -> s_load L2 miss), plus VALU
// inflation from AGPR-split weights (VGPR_Count=84; possibly the 73-operand
// "+s" asm constraint), plus 8-way bank conflicts on float4 pcomb (2.5e7).
// Fix: h/hx state lives in LDS. Each wave pulls the 73 state dwords it needs
// with TWO lane-indexed ds_read_b32 (distinct dword per lane = bandwidth-
// efficient), then v_readlane moves them to SGPRs; v_dot2_f32_f16 takes the
// SGPR broadcast operand for free. No global state traffic, no s_dcache_inv,
// no inline asm. pcomb split into 4 scalar planes (stride 4B, conflict-free).
// K-split wave-uniform (waves 0-5 = half0 of all 384 rows, 6-11 = half1);
// updater waves 8,9 = h0 units, 10,11 = h1 units (L1 staggered one step).
// 2 barriers/step.

#define BB 256
#define SS 1024
#define DD 32
#define HH 128
#define NT 768

typedef _Float16 f16;
typedef __attribute__((ext_vector_type(2))) _Float16 h2;

__device__ inline h2 as_h2(int x) { union { int i; h2 h; } u; u.i = x; return u.h; }

__device__ inline float dot2(h2 a, h2 b, float c) {
    return __builtin_amdgcn_fdot2(a, b, c, false);
}

__device__ inline float frcp(float x) { return __builtin_amdgcn_rcpf(x); }
__device__ inline float fast_sigm(float x) { return frcp(1.0f + __expf(-x)); }
__device__ inline float fast_tanh(float x) {
    x = fminf(15.0f, fmaxf(-15.0f, x));
    float e = __expf(-2.0f * x);
    return (1.0f - e) * frcp(1.0f + e);
}

struct ImpState { float xprev, tprev; bool hasprev; };

// Wave 0 only (all 64 lanes active). Lane l<32 owns feature l; writes the
// LDS hx slot consumed by the lane-indexed state read next iteration.
__device__ inline void impute_store(int i, float xv, int l, ImpState& st,
                                    f16* hxf, const float* tb) {
    bool nanp = (l < 32) && (xv != xv);
    unsigned long long bal = __ballot(nanp);
    bool mask = bal != 0ull;
    if (l < 32) {
        float imp = mask ? st.xprev : xv;
        hxf[l] = (f16)imp;
        if (!mask) st.xprev = xv;
    }
    float tcur = tb[i];
    float tdel = (i == 0) ? 0.0f : (tcur - tb[i - 1]);
    float texp = st.hasprev ? (tcur - st.tprev) : tdel;
    if (l == 32) hxf[32] = (f16)(mask ? 1.0f : 0.0f);
    if (l == 33) hxf[33] = (f16)texp;
    if (!mask) { st.hasprev = true; st.tprev = tcur; }
}

__global__ __launch_bounds__(NT, 3) void gru_fused(
    const float* __restrict__ t_in, const float* __restrict__ x_in,
    const float* __restrict__ Wih0, const float* __restrict__ Whh0,
    const float* __restrict__ bih0, const float* __restrict__ bhh0,
    const float* __restrict__ Wih1, const float* __restrict__ Whh1,
    const float* __restrict__ bih1, const float* __restrict__ bhh1,
    float* __restrict__ out)
{
    __shared__ float tb[SS];        // timestamps (4 KB)
    __shared__ int stDW[152];       // h0: dw[0:64), h1: dw[64:128), hx: dw[128:145)
    __shared__ float pA[NT], pC[NT], pD[NT], pE[NT];   // partial planes (12 KB)

    const int tid = threadIdx.x;
    const int b = blockIdx.x;
    const int group = tid >= 384;       // K-half, wave-uniform (waves 0-5 / 6-11)
    const int row = tid - 384 * group;  // gate row 0..383
    const int lane = tid & 63;

    // ---- pack this thread's half-rows into registers (f32 -> f16x2) ----
    h2 wih0[9], whh0[32], wih1[32], whh1[32];
    {
        const float* p = Wih0 + row * 34;
        const int lim = 8 + group;      // group0: 8 real pairs (+1 zero pad), group1: 9
        #pragma unroll
        for (int k = 0; k < 9; k++) {
            int e = 16 * group + 2 * k;
            f16 lo = (k < lim) ? (f16)p[e]     : (f16)0.0f;
            f16 hi = (k < lim) ? (f16)p[e + 1] : (f16)0.0f;
            h2 v = {lo, hi}; wih0[k] = v;
        }
        p = Whh0 + row * HH + 64 * group;
        #pragma unroll
        for (int k = 0; k < 32; k++) { h2 v = {(f16)p[2*k], (f16)p[2*k+1]}; whh0[k] = v; }
        p = Wih1 + row * HH + 64 * group;
        #pragma unroll
        for (int k = 0; k < 32; k++) { h2 v = {(f16)p[2*k], (f16)p[2*k+1]}; wih1[k] = v; }
        p = Whh1 + row * HH + 64 * group;
        #pragma unroll
        for (int k = 0; k < 32; k++) { h2 v = {(f16)p[2*k], (f16)p[2*k+1]}; whh1[k] = v; }
    }

    // ---- updater setup: waves 8,9 -> h0 units; waves 10,11 -> h1 units ----
    const bool isU = (tid >= 512);
    const bool isU0 = (tid >= 512 && tid < 640);
    const int j = isU0 ? (tid - 512) : (tid - 640);
    float ubi[3], ubh[3]; float hr = 0.0f;
    if (isU) {
        const float* bi = isU0 ? bih0 : bih1;
        const float* bh = isU0 ? bhh0 : bhh1;
        #pragma unroll
        for (int q = 0; q < 3; q++) { ubi[q] = bi[j + 128*q]; ubh[q] = bh[j + 128*q]; }
    }

    // ---- lane-indexed state-read addresses (constant across the loop) ----
    // read A: lanes 0-31 -> h0 dword (32*group + lane); lanes 32-63 -> h1 dword.
    const int idxA = (lane < 32) ? (32 * group + lane)
                                 : (64 + 32 * group + (lane - 32));
    // read B: lanes 0-8 -> hx dword (8*group + lane); others read a safe dword.
    const int idxB = 128 + 8 * group + ((lane < 9) ? lane : 0);

    // ---- prologue ----
    for (int i2 = tid; i2 < SS; i2 += NT) tb[i2] = t_in[i2];
    if (tid < 152) stDW[tid] = 0;

    f16* h0f = (f16*)&stDW[0];
    f16* h1f = (f16*)&stDW[64];
    f16* hxf = (f16*)&stDW[128];

    const float* xrow = x_in + (size_t)b * SS * DD + tid;   // deref only tid<32
    ImpState st; st.xprev = 0.0f; st.tprev = 0.0f; st.hasprev = false;

    __syncthreads();
    if (tid < 64) {
        float xv0 = (tid < 32) ? xrow[0] : 0.0f;
        impute_store(0, xv0, tid, st, hxf, tb);
    }
    __syncthreads();

    for (int i = 0; i <= SS; ++i) {
        const bool doL0 = (i < SS), doL1 = (i > 0), doImp = (i + 1 < SS);

        // lane-indexed state reads (one distinct dword per lane)
        int vA = stDW[idxA];
        int vB = stDW[idxB];

        // prefetch next x row for imputation (overlaps latency)
        float xv_n = 0.0f;
        if (tid < 32 && doImp) xv_n = xrow[(size_t)(i + 1) * DD];

        // broadcast state to SGPRs via readlane
        int h0u[32], h1u[32], hxu[9];
        #pragma unroll
        for (int k = 0; k < 32; k++) h0u[k] = __builtin_amdgcn_readlane(vA, k);
        #pragma unroll
        for (int k = 0; k < 32; k++) h1u[k] = __builtin_amdgcn_readlane(vA, 32 + k);
        #pragma unroll
        for (int k = 0; k < 9; k++)  hxu[k] = __builtin_amdgcn_readlane(vB, k);

        // ---- dots: h-operands broadcast from SGPRs, weights in VGPRs ----
        float aP = 0.0f;
        #pragma unroll
        for (int k = 0; k < 9; k++) aP = dot2(as_h2(hxu[k]), wih0[k], aP);
        float cC[4] = {0,0,0,0}, dC[4] = {0,0,0,0}, eC[4] = {0,0,0,0};
        #pragma unroll
        for (int k = 0; k < 32; k++) {
            h2 hh = as_h2(h0u[k]);
            cC[k & 3] = dot2(hh, whh0[k], cC[k & 3]);
            dC[k & 3] = dot2(hh, wih1[k], dC[k & 3]);
        }
        #pragma unroll
        for (int k = 0; k < 32; k++) {
            h2 hh = as_h2(h1u[k]);
            eC[k & 3] = dot2(hh, whh1[k], eC[k & 3]);
        }
        pA[tid] = aP;
        pC[tid] = (cC[0] + cC[1]) + (cC[2] + cC[3]);
        pD[tid] = (dC[0] + dC[1]) + (dC[2] + dC[3]);
        pE[tid] = (eC[0] + eC[1]) + (eC[2] + eC[3]);
        __syncthreads();   // B1

        // ---- update phase ----
        if (isU) {
            bool act = isU0 ? doL0 : doL1;
            if (act) {
                float rx, rh, zx, zh, nx, nh;
                if (isU0) {   // layer 0: gx from pA, gh from pC
                    rx = pA[j]       + pA[384 + j];       rh = pC[j]       + pC[384 + j];
                    zx = pA[j + 128] + pA[384 + j + 128]; zh = pC[j + 128] + pC[384 + j + 128];
                    nx = pA[j + 256] + pA[384 + j + 256]; nh = pC[j + 256] + pC[384 + j + 256];
                } else {      // layer 1: gx from pD, gh from pE
                    rx = pD[j]       + pD[384 + j];       rh = pE[j]       + pE[384 + j];
                    zx = pD[j + 128] + pD[384 + j + 128]; zh = pE[j + 128] + pE[384 + j + 128];
                    nx = pD[j + 256] + pD[384 + j + 256]; nh = pE[j + 256] + pE[384 + j + 256];
                }
                float r = fast_sigm(ubi[0] + ubh[0] + rx + rh);
                float z = fast_sigm(ubi[1] + ubh[1] + zx + zh);
                float n = fast_tanh(ubi[2] + nx + r * (ubh[2] + nh));
                hr = (1.0f - z) * n + z * hr;
                (isU0 ? h0f : h1f)[j] = (f16)hr;   // LDS f16 store
            }
        } else if (tid < 64 && doImp) {
            impute_store(i + 1, xv_n, tid, st, hxf, tb);
        }
        __syncthreads();   // B2 (lgkm drain -> state visible)
    }

    if (tid >= 640) out[(size_t)b * HH + (tid - 640)] = hr;
}

extern "C" void kernel_launch(void* const* d_in, const int* in_sizes, int n_in,
                              void* d_out, int out_size, void* d_ws, size_t ws_size,
                              hipStream_t stream) {
    gru_fused<<<dim3(BB), dim3(NT), 0, stream>>>(
        (const float*)d_in[0], (const float*)d_in[1],
        (const float*)d_in[2], (const float*)d_in[3],
        (const float*)d_in[4], (const float*)d_in[5],
        (const float*)d_in[6], (const float*)d_in[7],
        (const float*)d_in[8], (const float*)d_in[9],
        (float*)d_out);
}

// Round 8
// 1548.119 us; speedup vs baseline: 1.0139x; 1.0139x over previous
//
#include <hip/hip_runtime.h>
#include <hip/hip_bf16.h>

// GRU-D fused scan, 8-wave full-K edition.
// R7 diagnosis: with 12 waves/block the per-wave register budget is 512/3=170,
// which the compiler splits 84 arch VGPR + 84 AGPR (VGPR_Count=84 every round)
// -> v_accvgpr_read around ~half the dot operands = the unexplained VALU
// inflation (2700 busy cyc/SIMD/step vs ~1500 modeled).
// Fix: 512 threads / 8 waves (__launch_bounds__(512,2)) -> 256 arch VGPRs.
// Full-K rows (no K-split): waves 0-5 thread r owns Whh0[r]+Wih1[r] (share the
// h0 operand broadcast: 64 readlanes feed 128 dots) + Wih0[r] (17 h2) = 145 h2;
// waves 6-7 own 3 full Whh1 rows (192 h2; 64 rl feed 192 dots). Each thread
// produces COMPLETE gate pre-activation components -> no cross-lane combine.
// Weights live in ONE w[192] array loaded divergently so the allocator doesn't
// union two live arrays. State (h0/h1/hx f16) in LDS; per-wave delivery =
// 1-2 lane-indexed ds_read_b32 + readlanes to SGPRs (v_dot2 broadcast src).
// Update: wave 6 = h0 units (2/lane), wave 7 = h1 units, wave 0 = impute.
// 2 barriers/step, staggered L1 (iteration i: L0 step i, L1 step i-1).

#define BB 256
#define SS 1024
#define DD 32
#define HH 128
#define NT 512

typedef _Float16 f16;
typedef __attribute__((ext_vector_type(2))) _Float16 h2;

__device__ inline h2 as_h2(int x) { union { int i; h2 h; } u; u.i = x; return u.h; }

__device__ inline float dot2(h2 a, h2 b, float c) {
    return __builtin_amdgcn_fdot2(a, b, c, false);
}

__device__ inline float frcp(float x) { return __builtin_amdgcn_rcpf(x); }
__device__ inline float fast_sigm(float x) { return frcp(1.0f + __expf(-x)); }
__device__ inline float fast_tanh(float x) {
    x = fminf(15.0f, fmaxf(-15.0f, x));
    float e = __expf(-2.0f * x);
    return (1.0f - e) * frcp(1.0f + e);
}

struct ImpState { float xprev, tprev; bool hasprev; };

// Wave 0 only (all 64 lanes execute; lane l<32 owns feature l).
__device__ inline void impute_store(int i, float xv, int l, ImpState& st,
                                    f16* hxf, const float* tb) {
    bool nanp = (l < 32) && (xv != xv);
    unsigned long long bal = __ballot(nanp);
    bool mask = bal != 0ull;
    if (l < 32) {
        float imp = mask ? st.xprev : xv;
        hxf[l] = (f16)imp;
        if (!mask) st.xprev = xv;
    }
    float tcur = tb[i];
    float tdel = (i == 0) ? 0.0f : (tcur - tb[i - 1]);
    float texp = st.hasprev ? (tcur - st.tprev) : tdel;
    if (l == 32) hxf[32] = (f16)(mask ? 1.0f : 0.0f);
    if (l == 33) hxf[33] = (f16)texp;
    if (!mask) { st.hasprev = true; st.tprev = tcur; }
}

__global__ __launch_bounds__(NT, 2) void gru_fused(
    const float* __restrict__ t_in, const float* __restrict__ x_in,
    const float* __restrict__ Wih0, const float* __restrict__ Whh0,
    const float* __restrict__ bih0, const float* __restrict__ bhh0,
    const float* __restrict__ Wih1, const float* __restrict__ Whh1,
    const float* __restrict__ bih1, const float* __restrict__ bhh1,
    float* __restrict__ out)
{
    __shared__ float tb[SS];        // timestamps (4 KB)
    __shared__ int stDW[145];       // h0: dw[0,64) h1: dw[64,128) hx: dw[128,145)
    __shared__ float pGX0[384], pGH0[384], pGX1[384], pGH1[384];  // 6 KB

    const int tid = threadIdx.x;
    const int lane = tid & 63;
    const int b = blockIdx.x;
    const bool isDot = (tid < 384);      // waves 0-5

    // ---- weights: ONE array, loaded divergently (no union-allocation blowup) ----
    h2 w[192];
    if (isDot) {
        const float* pa = Whh0 + tid * HH;     // row tid, K=128
        const float* pb = Wih1 + tid * HH;
        const float* pc = Wih0 + tid * 34;
        #pragma unroll
        for (int k = 0; k < 64; k++) { h2 v = {(f16)pa[2*k], (f16)pa[2*k+1]}; w[k] = v; }
        #pragma unroll
        for (int k = 0; k < 64; k++) { h2 v = {(f16)pb[2*k], (f16)pb[2*k+1]}; w[64+k] = v; }
        #pragma unroll
        for (int k = 0; k < 17; k++) { h2 v = {(f16)pc[2*k], (f16)pc[2*k+1]}; w[128+k] = v; }
        #pragma unroll
        for (int k = 145; k < 192; k++) { h2 v = {(f16)0.0f, (f16)0.0f}; w[k] = v; }
    } else {
        const int gl = tid - 384;              // 0..127
        const float* p0 = Whh1 + (size_t)gl * HH;
        const float* p1 = Whh1 + (size_t)(gl + 128) * HH;
        const float* p2 = Whh1 + (size_t)(gl + 256) * HH;
        #pragma unroll
        for (int k = 0; k < 64; k++) { h2 v = {(f16)p0[2*k], (f16)p0[2*k+1]}; w[k] = v; }
        #pragma unroll
        for (int k = 0; k < 64; k++) { h2 v = {(f16)p1[2*k], (f16)p1[2*k+1]}; w[64+k] = v; }
        #pragma unroll
        for (int k = 0; k < 64; k++) { h2 v = {(f16)p2[2*k], (f16)p2[2*k+1]}; w[128+k] = v; }
    }

    // ---- updater bias preload (waves 6,7: units 2*lane, 2*lane+1) ----
    float hra = 0.0f, hrb = 0.0f;
    float bra = 0, bza = 0, bina = 0, bhna = 0, brb = 0, bzb = 0, binb = 0, bhnb = 0;
    if (!isDot) {
        const bool u0 = (tid < 448);           // wave 6 -> h0, wave 7 -> h1
        const float* bi = u0 ? bih0 : bih1;
        const float* bh = u0 ? bhh0 : bhh1;
        const int ua = 2 * lane, ub = ua + 1;
        bra = bi[ua] + bh[ua];       bza = bi[ua+128] + bh[ua+128];
        bina = bi[ua+256];           bhna = bh[ua+256];
        brb = bi[ub] + bh[ub];       bzb = bi[ub+128] + bh[ub+128];
        binb = bi[ub+256];           bhnb = bh[ub+256];
    }

    // ---- prologue: tb, zero h state, impute(0) ----
    for (int i2 = tid; i2 < SS; i2 += NT) tb[i2] = t_in[i2];
    if (tid < 128) stDW[tid] = 0;
    f16* hxf = (f16*)&stDW[128];

    const float* xrow = x_in + (size_t)b * SS * DD + tid;   // deref only tid<32
    ImpState st; st.xprev = 0.0f; st.tprev = 0.0f; st.hasprev = false;

    __syncthreads();
    if (tid < 64) {
        float xv0 = (tid < 32) ? xrow[0] : 0.0f;
        impute_store(0, xv0, tid, st, hxf, tb);
    }
    __syncthreads();

    // lane-indexed state-read addresses (loop-invariant)
    const int idxA = isDot ? lane : (64 + lane);            // h0 / h1 dword
    const int idxB = 128 + ((lane < 17) ? lane : 0);        // hx dword (waves 0-5)

    for (int i = 0; i <= SS; ++i) {
        const bool doL0 = (i < SS), doL1 = (i > 0), doImp = (i + 1 < SS);

        int vA = stDW[idxA];

        // prefetch next x row (consumed in impute after B1)
        float xv_n = 0.0f;
        if (tid < 32 && doImp) xv_n = xrow[(size_t)(i + 1) * DD];

        if (isDot) {
            int vB = stDW[idxB];
            float aGH0 = 0.0f, aGX1 = 0.0f, aGX0 = 0.0f;
            #pragma unroll
            for (int k = 0; k < 64; k++) {
                h2 s = as_h2(__builtin_amdgcn_readlane(vA, k));   // h0[2k:2k+1]
                aGH0 = dot2(s, w[k],      aGH0);
                aGX1 = dot2(s, w[64 + k], aGX1);
            }
            #pragma unroll
            for (int k = 0; k < 17; k++) {
                h2 s = as_h2(__builtin_amdgcn_readlane(vB, k));   // hx[2k:2k+1]
                aGX0 = dot2(s, w[128 + k], aGX0);
            }
            pGH0[tid] = aGH0; pGX1[tid] = aGX1; pGX0[tid] = aGX0;
        } else {
            const int gl = tid - 384;
            float a0 = 0.0f, a1 = 0.0f, a2 = 0.0f;
            #pragma unroll
            for (int k = 0; k < 64; k++) {
                h2 s = as_h2(__builtin_amdgcn_readlane(vA, k));   // h1[2k:2k+1]
                a0 = dot2(s, w[k],       a0);
                a1 = dot2(s, w[64 + k],  a1);
                a2 = dot2(s, w[128 + k], a2);
            }
            pGH1[gl] = a0; pGH1[gl + 128] = a1; pGH1[gl + 256] = a2;
        }
        __syncthreads();   // B1: partials visible, state reads done

        if (!isDot) {
            const bool u0 = (tid < 448);
            if (u0 ? doL0 : doL1) {
                const float* gx = u0 ? pGX0 : pGX1;
                const float* gh = u0 ? pGH0 : pGH1;
                const int ua = 2 * lane, ub = ua + 1;
                float r0 = fast_sigm(bra + gx[ua] + gh[ua]);
                float z0 = fast_sigm(bza + gx[ua+128] + gh[ua+128]);
                float n0 = fast_tanh(bina + gx[ua+256] + r0 * (bhna + gh[ua+256]));
                hra = (1.0f - z0) * n0 + z0 * hra;
                float r1 = fast_sigm(brb + gx[ub] + gh[ub]);
                float z1 = fast_sigm(bzb + gx[ub+128] + gh[ub+128]);
                float n1 = fast_tanh(binb + gx[ub+256] + r1 * (bhnb + gh[ub+256]));
                hrb = (1.0f - z1) * n1 + z1 * hrb;
                h2 hv = {(f16)hra, (f16)hrb};               // f16 idx 2l,2l+1 = dword l
                ((h2*)stDW)[(u0 ? 0 : 64) + lane] = hv;
            }
        } else if (tid < 64 && doImp) {
            impute_store(i + 1, xv_n, tid, st, hxf, tb);
        }
        __syncthreads();   // B2: state stores visible
    }

    if (tid >= 448) {   // wave 7 holds final h1 (units 2*lane, 2*lane+1)
        float2 o = make_float2(hra, hrb);
        *(float2*)&out[(size_t)b * HH + 2 * lane] = o;
    }
}

extern "C" void kernel_launch(void* const* d_in, const int* in_sizes, int n_in,
                              void* d_out, int out_size, void* d_ws, size_t ws_size,
                              hipStream_t stream) {
    gru_fused<<<dim3(BB), dim3(NT), 0, stream>>>(
        (const float*)d_in[0], (const float*)d_in[1],
        (const float*)d_in[2], (const float*)d_in[3],
        (const float*)d_in[4], (const float*)d_in[5],
        (const float*)d_in[6], (const float*)d_in[7],
        (const float*)d_in[8], (const float*)d_in[9],
        (float*)d_out);
}